// Round 10
// baseline (248.481 us; speedup 1.0000x reference)
//
#include <hip/hip_runtime.h>
#include <hip/hip_bf16.h>
#include <stdint.h>

#define B_N 8
#define T_N 2048
#define FDIM_N 512
#define H_N 8
#define DK_N 64

typedef float f32x4 __attribute__((ext_vector_type(4)));
typedef float float4v __attribute__((ext_vector_type(4)));
typedef __bf16 bf16x8 __attribute__((ext_vector_type(8)));
typedef unsigned short ushort8v __attribute__((ext_vector_type(8)));
typedef unsigned int uint2v __attribute__((ext_vector_type(2)));
typedef unsigned int uint4v __attribute__((ext_vector_type(4)));

#if __has_builtin(__builtin_amdgcn_exp2f)
#define EXP2F(x) __builtin_amdgcn_exp2f(x)
#else
#define EXP2F(x) exp2f(x)
#endif

static __device__ __forceinline__ unsigned short f2bf(float f) {
  unsigned int u = __builtin_bit_cast(unsigned int, f);
  u += 0x7fffu + ((u >> 16) & 1u);
  return (unsigned short)(u >> 16);
}

// v_cvt_pk_bf16_f32: lo -> bits[15:0], hi -> bits[31:16] (RNE)
static __device__ __forceinline__ unsigned cvtpk(float lo, float hi) {
  unsigned r;
  asm("v_cvt_pk_bf16_f32 %0, %1, %2" : "=v"(r) : "v"(lo), "v"(hi));
  return r;
}

static __device__ __forceinline__ void gld_lds16(const void* g, void* l) {
  __builtin_amdgcn_global_load_lds(
      (const __attribute__((address_space(1))) unsigned int*)g,
      (__attribute__((address_space(3))) unsigned int*)l, 16, 0, 0);
}

static __device__ __forceinline__ bf16x8 ld_bf8(const unsigned short* p) {
  return *reinterpret_cast<const bf16x8*>(p);
}

// elem-offset XOR swizzle for 64-elem bf16 rows (8-elem granules)
#define SWZ8(row, colE) ((colE) ^ (((row) & 7) << 3))

// combined softmax scale: 1/sqrt(64) * log2(e)  (exp2-domain softmax, no-max)
#define QSCALE 0.1803368801111244f

// ---------------- prep: mask pack + weight cvt + input cvt (all BW-bound) ----
// blocks [0,2048): mask int32 -> u64 bitmask (grid-stride)
// blocks [2048,2560): 4 weights f32 -> bf16
// blocks [2560,4096): q,k,v f32 -> bf16 (grid-stride over 3 x 2^20 chunks)
__global__ __launch_bounds__(256) void prep_k(
    const int* __restrict__ m, const float* __restrict__ w0, const float* __restrict__ w1,
    const float* __restrict__ w2, const float* __restrict__ w3,
    const float* __restrict__ qin, const float* __restrict__ kin, const float* __restrict__ vin,
    unsigned short* __restrict__ wb, unsigned short* __restrict__ qb,
    unsigned short* __restrict__ kb, unsigned short* __restrict__ vb,
    unsigned long long* __restrict__ mbits) {
  const int bid = blockIdx.x;
  if (bid < 2048) {
    const size_t n = (size_t)B_N * T_N * T_N;
    const size_t stride = (size_t)2048 * 256;
    for (size_t i = (size_t)bid * 256 + threadIdx.x; i < n; i += stride) {
      unsigned long long bl = __ballot(m[i] != 0);
      if ((threadIdx.x & 63) == 0) mbits[i >> 6] = bl;
    }
  } else if (bid < 2560) {
    const int i = (bid - 2048) * 256 + threadIdx.x;  // [0, 131072)
    const int ws = i >> 15, o = i & 32767;
    const float* w = (ws == 0) ? w0 : (ws == 1) ? w1 : (ws == 2) ? w2 : w3;
    const float4v a = *reinterpret_cast<const float4v*>(w + (size_t)o * 8);
    const float4v b = *reinterpret_cast<const float4v*>(w + (size_t)o * 8 + 4);
    const ushort8v out = {f2bf(a.x), f2bf(a.y), f2bf(a.z), f2bf(a.w),
                          f2bf(b.x), f2bf(b.y), f2bf(b.z), f2bf(b.w)};
    *reinterpret_cast<ushort8v*>(wb + (size_t)i * 8) = out;
  } else {
    const unsigned total = 3u << 20;  // 3 x 2^20 ushort8-chunks
    const unsigned stride = 1536u * 256u;
    for (unsigned i = (bid - 2560) * 256 + threadIdx.x; i < total; i += stride) {
      const unsigned sel = i >> 20, off = i & 0xFFFFFu;
      const float* in = (sel == 0) ? qin : (sel == 1) ? kin : vin;
      unsigned short* out = (sel == 0) ? qb : (sel == 1) ? kb : vb;
      const float4v a = *reinterpret_cast<const float4v*>(in + (size_t)off * 8);
      const float4v b = *reinterpret_cast<const float4v*>(in + (size_t)off * 8 + 4);
      const ushort8v o = {f2bf(a.x), f2bf(a.y), f2bf(a.z), f2bf(a.w),
                          f2bf(b.x), f2bf(b.y), f2bf(b.z), f2bf(b.w)};
      *reinterpret_cast<ushort8v*>(out + (size_t)i * 8) = o;  // i spans q|k|v contiguously? no:
      // NOTE: out is per-input base, so index with off (not i):
    }
  }
}

// (see corrected cvt below — kept in a dedicated kernel to avoid the indexing
//  subtlety above; prep_k handles mask+weights only)

__global__ __launch_bounds__(256) void cvt3_k(const float* __restrict__ qin,
                                              const float* __restrict__ kin,
                                              const float* __restrict__ vin,
                                              unsigned short* __restrict__ qb,
                                              unsigned short* __restrict__ kb,
                                              unsigned short* __restrict__ vb) {
  const unsigned total = 3u << 20;
  const unsigned stride = gridDim.x * 256u;
  for (unsigned i = blockIdx.x * 256 + threadIdx.x; i < total; i += stride) {
    const unsigned sel = i >> 20, off = i & 0xFFFFFu;
    const float* in = (sel == 0) ? qin : (sel == 1) ? kin : vin;
    unsigned short* out = (sel == 0) ? qb : (sel == 1) ? kb : vb;
    const float4v a = *reinterpret_cast<const float4v*>(in + (size_t)off * 8);
    const float4v b = *reinterpret_cast<const float4v*>(in + (size_t)off * 8 + 4);
    const ushort8v o = {f2bf(a.x), f2bf(a.y), f2bf(a.z), f2bf(a.w),
                        f2bf(b.x), f2bf(b.y), f2bf(b.z), f2bf(b.w)};
    *reinterpret_cast<ushort8v*>(out + (size_t)off * 8) = o;
  }
}

// ---------------- batched projection GEMM, all-bf16 m97 pattern [R3-proven] ---
// gb=0: q (QSCALE, layout0)  gb=1: k (layout0)  gb=2: v (V^T + pi permute)
__global__ __launch_bounds__(256, 3) void proj3_k(
    const unsigned short* __restrict__ qb, const unsigned short* __restrict__ kb,
    const unsigned short* __restrict__ vb, const unsigned short* __restrict__ wb,
    const float* __restrict__ bq, const float* __restrict__ bk, const float* __restrict__ bv,
    unsigned short* __restrict__ q_scr, unsigned short* __restrict__ k_scr,
    unsigned short* __restrict__ vT_scr) {
  __shared__ unsigned short As[128 * 64];
  __shared__ unsigned short Bs[128 * 64];
  const int tid = threadIdx.x;
  const int lane = tid & 63, w = tid >> 6;
  const int lr = lane & 15, lg = lane >> 4;
  const int id = blockIdx.x;
  const int work = (id & 7) * 192 + (id >> 3);  // XCD swizzle over 1536
  const int gb = work / 512;
  const int wk = work - gb * 512;
  const int m0 = (wk >> 2) * 128, n0 = (wk & 3) * 128;
  const int wm = (w & 1) * 64, wn = (w >> 1) * 64;
  const int swz_rd = (lr & 7) << 3;

  const unsigned short* Ap = (gb == 0) ? qb : (gb == 1) ? kb : vb;
  const unsigned short* Wp = wb + (size_t)gb * 262144;
  const float* biasp = (gb == 0) ? bq : (gb == 1) ? bk : bv;

  f32x4 acc[4][4];
  const f32x4 z4 = {0.f, 0.f, 0.f, 0.f};
#pragma unroll
  for (int i = 0; i < 4; ++i)
#pragma unroll
    for (int j = 0; j < 4; ++j) acc[i][j] = z4;

  for (int k0 = 0; k0 < 512; k0 += 64) {
    __syncthreads();
#pragma unroll
    for (int i = 0; i < 4; ++i) {
      const int c = i * 256 + tid;
      const int row = c >> 3, ch = c & 7;
      const int sw = SWZ8(row, ch * 8);
      gld_lds16(Ap + (size_t)(m0 + row) * 512 + k0 + sw, &As[c * 8]);
      gld_lds16(Wp + (size_t)(n0 + row) * 512 + k0 + sw, &Bs[c * 8]);
    }
    __syncthreads();
    bf16x8 af[4][2], bw[4][2];
#pragma unroll
    for (int mt = 0; mt < 4; ++mt)
#pragma unroll
      for (int kk = 0; kk < 2; ++kk)
        af[mt][kk] = ld_bf8(&As[(wm + mt * 16 + lr) * 64 + ((kk * 32 + lg * 8) ^ swz_rd)]);
#pragma unroll
    for (int nt = 0; nt < 4; ++nt)
#pragma unroll
      for (int kk = 0; kk < 2; ++kk)
        bw[nt][kk] = ld_bf8(&Bs[(wn + nt * 16 + lr) * 64 + ((kk * 32 + lg * 8) ^ swz_rd)]);
#pragma unroll
    for (int kk = 0; kk < 2; ++kk)
#pragma unroll
      for (int mt = 0; mt < 4; ++mt)
#pragma unroll
        for (int nt = 0; nt < 4; ++nt)
          acc[mt][nt] =
              __builtin_amdgcn_mfma_f32_16x16x32_bf16(af[mt][kk], bw[nt][kk], acc[mt][nt], 0, 0, 0);
  }

#pragma unroll
  for (int nt = 0; nt < 4; ++nt) {
    const int n = n0 + wn + nt * 16 + lr;
    const float bias = biasp[n];
#pragma unroll
    for (int mt = 0; mt < 4; ++mt) {
#pragma unroll
      for (int j = 0; j < 4; ++j) {
        const int m = m0 + wm + mt * 16 + lg * 4 + j;
        float v = acc[mt][nt][j] + bias;
        const int bb = m >> 11, t = m & 2047;
        const int hh = n >> 6, d = n & 63;
        if (gb == 0) {
          v *= QSCALE;  // fold 1/sqrt(dk)*log2e into q
          q_scr[(((size_t)(bb * 8 + hh) * 2048 + t) << 6) + d] = f2bf(v);
        } else if (gb == 1) {
          k_scr[(((size_t)(bb * 8 + hh) * 2048 + t) << 6) + d] = f2bf(v);
        } else {
          // pi: bits {0,1}->{0,1}, {2,3}->{3,4}, {4}->{2} within each 32-block
          const int tp = (t & ~31) | (((t >> 2) & 3) << 3) | (((t >> 4) & 1) << 2) | (t & 3);
          vT_scr[(((size_t)(bb * 8 + hh) * 64 + d) << 11) + tp] = f2bf(v);
        }
      }
    }
  }
}

// ---------------- flash attention: 8 waves x 16 q-rows, KVBLK=64 [R9-proven] --
__global__ __launch_bounds__(512, 4) void attn_k(
    const unsigned short* __restrict__ qg, const unsigned short* __restrict__ kg,
    const unsigned short* __restrict__ vtg, const unsigned long long* __restrict__ mb,
    unsigned short* __restrict__ xg) {
  __shared__ unsigned short Ks[2][64 * 64];
  __shared__ unsigned short Vts[2][64 * 64];

  const int tid = threadIdx.x;
  const int lane = tid & 63, w = tid >> 6;  // w in [0,8)
  const int lr = lane & 15, lg = lane >> 4;
  const int swz_rd = (lr & 7) << 3;
  const int id = blockIdx.x;
  const int work = (id & 7) * 128 + (id >> 3);  // XCD swizzle: one bh per XCD chunk
  const int bh = work >> 4, qt0 = work & 15;
  const int b = bh >> 3, h = bh & 7;
  const int q0 = qt0 * 128;

  bf16x8 aq[2];
#pragma unroll
  for (int kk = 0; kk < 2; ++kk)
    aq[kk] = ld_bf8(qg + ((size_t)bh * T_N + q0 + w * 16 + lr) * DK_N + kk * 32 + lg * 8);

  const int krow = tid >> 3, kch = tid & 7;
  const unsigned short* kp =
      kg + (size_t)bh * (T_N * DK_N) + krow * 64 + SWZ8(krow, kch * 8);
  const unsigned short* vp =
      vtg + ((size_t)bh * DK_N + krow) * T_N + SWZ8(krow, kch * 8);
  const unsigned long long* mp = mb + ((size_t)b * T_N + q0 + w * 16 + lr) * (T_N / 64);

  f32x4 OT[4];
  float rsacc = 0.f;
  const f32x4 z4 = {0.f, 0.f, 0.f, 0.f};
#pragma unroll
  for (int dt = 0; dt < 4; ++dt) OT[dt] = z4;

  f32x4 ST[4];
  bf16x8 pfrag[2];
  unsigned long long mc, mn = 0;

#define STAGE(PB)                        \
  {                                      \
    gld_lds16(kp, &Ks[PB][tid * 8]);     \
    gld_lds16(vp, &Vts[PB][tid * 8]);    \
    kp += 4096; vp += 64;                \
  }

#define QKT_BLOCK(CUR)                                                                      \
  {                                                                                         \
    __builtin_amdgcn_s_setprio(1);                                                          \
    _Pragma("unroll") for (int st = 0; st < 4; ++st) {                                      \
      const bf16x8 kb0 = ld_bf8(&Ks[CUR][(st * 16 + lr) * 64 + ((lg * 8) ^ swz_rd)]);       \
      const bf16x8 kb1 = ld_bf8(&Ks[CUR][(st * 16 + lr) * 64 + ((32 + lg * 8) ^ swz_rd)]);  \
      f32x4 a_ = __builtin_amdgcn_mfma_f32_16x16x32_bf16(kb0, aq[0], z4, 0, 0, 0);          \
      ST[st] = __builtin_amdgcn_mfma_f32_16x16x32_bf16(kb1, aq[1], a_, 0, 0, 0);            \
    }                                                                                       \
    __builtin_amdgcn_s_setprio(0);                                                          \
  }

#define SOFTMAX_BLOCK()                                                                     \
  {                                                                                         \
    float sv[4][4];                                                                         \
    _Pragma("unroll") for (int st = 0; st < 4; ++st) {                                      \
      const unsigned nib = (unsigned)(mc >> (st * 16 + lg * 4)) & 0xFu;                     \
      _Pragma("unroll") for (int j = 0; j < 4; ++j) {                                       \
        float e = EXP2F(ST[st][j]);                                                         \
        e = ((nib >> j) & 1u) ? 0.f : e;                                                    \
        sv[st][j] = e;                                                                      \
      }                                                                                     \
    }                                                                                       \
    rsacc += (((sv[0][0] + sv[0][1]) + (sv[0][2] + sv[0][3])) +                             \
              ((sv[1][0] + sv[1][1]) + (sv[1][2] + sv[1][3]))) +                            \
             (((sv[2][0] + sv[2][1]) + (sv[2][2] + sv[2][3])) +                             \
              ((sv[3][0] + sv[3][1]) + (sv[3][2] + sv[3][3])));                             \
    uint4v pk0_, pk1_;                                                                      \
    pk0_.x = cvtpk(sv[0][0], sv[0][1]); pk0_.y = cvtpk(sv[0][2], sv[0][3]);                 \
    pk0_.z = cvtpk(sv[1][0], sv[1][1]); pk0_.w = cvtpk(sv[1][2], sv[1][3]);                 \
    pk1_.x = cvtpk(sv[2][0], sv[2][1]); pk1_.y = cvtpk(sv[2][2], sv[2][3]);                 \
    pk1_.z = cvtpk(sv[3][0], sv[3][1]); pk1_.w = cvtpk(sv[3][2], sv[3][3]);                 \
    pfrag[0] = __builtin_bit_cast(bf16x8, pk0_);                                            \
    pfrag[1] = __builtin_bit_cast(bf16x8, pk1_);                                            \
  }

#define PV_BLOCK(PRV)                                                                       \
  {                                                                                         \
    __builtin_amdgcn_s_setprio(1);                                                          \
    _Pragma("unroll") for (int dt = 0; dt < 4; ++dt) {                                      \
      const bf16x8 v0 = ld_bf8(&Vts[PRV][(dt * 16 + lr) * 64 + ((lg * 8) ^ swz_rd)]);       \
      const bf16x8 v1 = ld_bf8(&Vts[PRV][(dt * 16 + lr) * 64 + ((32 + lg * 8) ^ swz_rd)]);  \
      f32x4 o_ = __builtin_amdgcn_mfma_f32_16x16x32_bf16(v0, pfrag[0], OT[dt], 0, 0, 0);    \
      OT[dt] = __builtin_amdgcn_mfma_f32_16x16x32_bf16(v1, pfrag[1], o_, 0, 0, 0);          \
    }                                                                                       \
    __builtin_amdgcn_s_setprio(0);                                                          \
  }

  STAGE(0);
  mc = mp[0];
  __syncthreads();
  QKT_BLOCK(0);
  STAGE(1);
  mn = mp[1];
  SOFTMAX_BLOCK();
  mc = mn;

#define ITER(KT, CUR, LAST)            \
  {                                    \
    PV_BLOCK(CUR ^ 1);                 \
    __syncthreads();                   \
    QKT_BLOCK(CUR);                    \
    if (!(LAST)) {                     \
      STAGE(CUR ^ 1);                  \
      mn = mp[(KT) + 1];               \
    }                                  \
    SOFTMAX_BLOCK();                   \
    mc = mn;                           \
  }

  ITER(1, 1, 0)
  for (int kt0 = 2; kt0 < 30; kt0 += 2) {
    ITER(kt0, 0, 0)
    ITER(kt0 + 1, 1, 0)
  }
  ITER(30, 0, 0)
  ITER(31, 1, 1)
  PV_BLOCK(1);
#undef ITER
#undef STAGE
#undef QKT_BLOCK
#undef SOFTMAX_BLOCK
#undef PV_BLOCK

  {
    float l = rsacc;
    l += __shfl_xor(l, 16);
    l += __shfl_xor(l, 32);
    const float inv = (l > 0.f) ? 1.f / l : 0.f;
    const int q = q0 + w * 16 + lr;
#pragma unroll
    for (int dt = 0; dt < 4; ++dt) {
      uint2v o;
      o.x = cvtpk(OT[dt][0] * inv, OT[dt][1] * inv);
      o.y = cvtpk(OT[dt][2] * inv, OT[dt][3] * inv);
      *reinterpret_cast<uint2v*>(xg + ((size_t)(b * T_N + q)) * FDIM_N + h * 64 + dt * 16 +
                                 lg * 4) = o;
    }
  }
}

// ---------------- output GEMM: bf16 A (x) @ Wo^T + bo -> f32 [R6-proven] ------
__global__ __launch_bounds__(256, 3) void gemm_out_k(const unsigned short* __restrict__ Ap,
                                                     const unsigned short* __restrict__ Wp,
                                                     const float* __restrict__ biasp,
                                                     float* __restrict__ Cp) {
  __shared__ unsigned short As[128 * 64];
  __shared__ unsigned short Bs[128 * 64];
  const int tid = threadIdx.x;
  const int lane = tid & 63, w = tid >> 6;
  const int lr = lane & 15, lg = lane >> 4;
  const int id = blockIdx.x;
  const int work = (id & 7) * 64 + (id >> 3);  // XCD swizzle over 512
  const int m0 = (work >> 2) * 128, n0 = (work & 3) * 128;
  const int wm = (w & 1) * 64, wn = (w >> 1) * 64;
  const int swz_rd = (lr & 7) << 3;

  f32x4 acc[4][4];
  const f32x4 z4 = {0.f, 0.f, 0.f, 0.f};
#pragma unroll
  for (int i = 0; i < 4; ++i)
#pragma unroll
    for (int j = 0; j < 4; ++j) acc[i][j] = z4;

  for (int k0 = 0; k0 < 512; k0 += 64) {
    __syncthreads();
#pragma unroll
    for (int i = 0; i < 4; ++i) {
      const int c = i * 256 + tid;
      const int row = c >> 3, ch = c & 7;
      const int sw = SWZ8(row, ch * 8);
      gld_lds16(Ap + (size_t)(m0 + row) * 512 + k0 + sw, &As[c * 8]);
      gld_lds16(Wp + (size_t)(n0 + row) * 512 + k0 + sw, &Bs[c * 8]);
    }
    __syncthreads();
    bf16x8 af[4][2], bw[4][2];
#pragma unroll
    for (int mt = 0; mt < 4; ++mt)
#pragma unroll
      for (int kk = 0; kk < 2; ++kk)
        af[mt][kk] = ld_bf8(&As[(wm + mt * 16 + lr) * 64 + ((kk * 32 + lg * 8) ^ swz_rd)]);
#pragma unroll
    for (int nt = 0; nt < 4; ++nt)
#pragma unroll
      for (int kk = 0; kk < 2; ++kk)
        bw[nt][kk] = ld_bf8(&Bs[(wn + nt * 16 + lr) * 64 + ((kk * 32 + lg * 8) ^ swz_rd)]);
#pragma unroll
    for (int kk = 0; kk < 2; ++kk)
#pragma unroll
      for (int mt = 0; mt < 4; ++mt)
#pragma unroll
        for (int nt = 0; nt < 4; ++nt)
          acc[mt][nt] =
              __builtin_amdgcn_mfma_f32_16x16x32_bf16(af[mt][kk], bw[nt][kk], acc[mt][nt], 0, 0, 0);
  }

#pragma unroll
  for (int nt = 0; nt < 4; ++nt) {
    const int n = n0 + wn + nt * 16 + lr;
    const float bias = biasp[n];
#pragma unroll
    for (int mt = 0; mt < 4; ++mt) {
#pragma unroll
      for (int j = 0; j < 4; ++j) {
        const int m = m0 + wm + mt * 16 + lg * 4 + j;
        Cp[(size_t)m * 512 + n] = acc[mt][nt][j] + bias;
      }
    }
  }
}

extern "C" void kernel_launch(void* const* d_in, const int* in_sizes, int n_in,
                              void* d_out, int out_size, void* d_ws, size_t ws_size,
                              hipStream_t stream) {
  const float* query = (const float*)d_in[0];
  const float* key = (const float*)d_in[1];
  const float* value = (const float*)d_in[2];
  const int* mask = (const int*)d_in[3];
  const float* Wq = (const float*)d_in[4];
  const float* bq = (const float*)d_in[5];
  const float* Wk = (const float*)d_in[6];
  const float* bk = (const float*)d_in[7];
  const float* Wv = (const float*)d_in[8];
  const float* bv = (const float*)d_in[9];
  const float* Wo = (const float*)d_in[10];
  const float* bo = (const float*)d_in[11];

  const size_t NE = (size_t)16384 * 512;
  const size_t WE = (size_t)512 * 512;
  unsigned short* qb_in = (unsigned short*)d_ws;     // bf16 inputs
  unsigned short* kb_in = qb_in + NE;
  unsigned short* vb_in = kb_in + NE;
  unsigned short* wqb = vb_in + NE;                  // 4 weights bf16
  unsigned short* q_scr = wqb + 4 * WE;
  unsigned short* k_scr = q_scr + NE;
  unsigned short* vT_scr = k_scr + NE;
  unsigned long long* mbits = (unsigned long long*)(vT_scr + NE);
  unsigned short* x_scr = qb_in;  // alias: qb_in dead after proj3

  prep_k<<<2560, 256, 0, stream>>>(mask, Wq, Wk, Wv, Wo, query, key, value, wqb, qb_in, kb_in,
                                   vb_in, mbits);
  cvt3_k<<<1536, 256, 0, stream>>>(query, key, value, qb_in, kb_in, vb_in);
  proj3_k<<<1536, 256, 0, stream>>>(qb_in, kb_in, vb_in, wqb, bq, bk, bv, q_scr, k_scr, vT_scr);
  attn_k<<<1024, 512, 0, stream>>>(q_scr, k_scr, vT_scr, mbits, x_scr);
  gemm_out_k<<<512, 256, 0, stream>>>(x_scr, wqb + 3 * WE, bo, (float*)d_out);
}

// Round 11
// 238.092 us; speedup vs baseline: 1.0436x; 1.0436x over previous
//
#include <hip/hip_runtime.h>
#include <hip/hip_bf16.h>
#include <stdint.h>

#define B_N 8
#define T_N 2048
#define FDIM_N 512
#define H_N 8
#define DK_N 64

typedef float f32x4 __attribute__((ext_vector_type(4)));
typedef float float4v __attribute__((ext_vector_type(4)));
typedef __bf16 bf16x8 __attribute__((ext_vector_type(8)));
typedef unsigned short ushort8v __attribute__((ext_vector_type(8)));
typedef unsigned int uint2v __attribute__((ext_vector_type(2)));
typedef unsigned int uint4v __attribute__((ext_vector_type(4)));

#if __has_builtin(__builtin_amdgcn_exp2f)
#define EXP2F(x) __builtin_amdgcn_exp2f(x)
#else
#define EXP2F(x) exp2f(x)
#endif

static __device__ __forceinline__ unsigned short f2bf(float f) {
  unsigned int u = __builtin_bit_cast(unsigned int, f);
  u += 0x7fffu + ((u >> 16) & 1u);
  return (unsigned short)(u >> 16);
}

// v_cvt_pk_bf16_f32: lo -> bits[15:0], hi -> bits[31:16] (RNE)
static __device__ __forceinline__ unsigned cvtpk(float lo, float hi) {
  unsigned r;
  asm("v_cvt_pk_bf16_f32 %0, %1, %2" : "=v"(r) : "v"(lo), "v"(hi));
  return r;
}

static __device__ __forceinline__ void gld_lds16(const void* g, void* l) {
  __builtin_amdgcn_global_load_lds(
      (const __attribute__((address_space(1))) unsigned int*)g,
      (__attribute__((address_space(3))) unsigned int*)l, 16, 0, 0);
}

static __device__ __forceinline__ bf16x8 ld_bf8(const unsigned short* p) {
  return *reinterpret_cast<const bf16x8*>(p);
}

// elem-offset XOR swizzle for 64-elem bf16 rows (8-elem granules)
#define SWZ8(row, colE) ((colE) ^ (((row) & 7) << 3))

// combined softmax scale: 1/sqrt(64) * log2(e)  (exp2-domain softmax, no-max)
#define QSCALE 0.1803368801111244f

// ---------------- prep: mask packing + weight f32->bf16 [R9-proven] ----------
__global__ __launch_bounds__(256) void prep_k(const int* __restrict__ m,
                                              const float* __restrict__ w0,
                                              const float* __restrict__ w1,
                                              const float* __restrict__ w2,
                                              const float* __restrict__ w3,
                                              unsigned short* __restrict__ wb,
                                              unsigned long long* __restrict__ mbits) {
  const int bid = blockIdx.x;
  if (bid < 2048) {
    const size_t n = (size_t)B_N * T_N * T_N;
    const size_t stride = (size_t)2048 * 256;
    for (size_t i = (size_t)bid * 256 + threadIdx.x; i < n; i += stride) {
      unsigned long long bl = __ballot(m[i] != 0);
      if ((threadIdx.x & 63) == 0) mbits[i >> 6] = bl;
    }
  } else {
    const int i = (bid - 2048) * 256 + threadIdx.x;  // [0, 131072)
    const int ws = i >> 15, o = i & 32767;
    const float* w = (ws == 0) ? w0 : (ws == 1) ? w1 : (ws == 2) ? w2 : w3;
    const float4v a = *reinterpret_cast<const float4v*>(w + (size_t)o * 8);
    const float4v b = *reinterpret_cast<const float4v*>(w + (size_t)o * 8 + 4);
    const ushort8v out = {f2bf(a.x), f2bf(a.y), f2bf(a.z), f2bf(a.w),
                          f2bf(b.x), f2bf(b.y), f2bf(b.z), f2bf(b.w)};
    *reinterpret_cast<ushort8v*>(wb + (size_t)i * 8) = out;
  }
}

// ---------------- batched projection GEMM (q,k,v in one launch) ----------------
// R9 structure with ONE fix: the next-K A prefetch is issued AFTER the staging
// barrier (was: immediately before it, where the barrier's implicit vmcnt(0)
// drained it synchronously with zero overlap). Now it overlaps the full MFMA
// phase and drains at the NEXT iteration's first barrier. Regs are dead after
// the ds_write, so no double buffer is needed.
__global__ __launch_bounds__(256, 2) void proj_k(
    const float* __restrict__ qin, const float* __restrict__ kin, const float* __restrict__ vin,
    const unsigned short* __restrict__ wb, const float* __restrict__ bq,
    const float* __restrict__ bk, const float* __restrict__ bv,
    unsigned short* __restrict__ q_scr, unsigned short* __restrict__ k_scr,
    unsigned short* __restrict__ vT_scr) {
  __shared__ unsigned short As[128 * 64];
  __shared__ unsigned short Bs[128 * 64];
  const int tid = threadIdx.x;
  const int lane = tid & 63, w = tid >> 6;
  const int lr = lane & 15, lg = lane >> 4;
  const int swz_rd = (lr & 7) << 3;
  const int id = blockIdx.x;
  const int work = (id & 7) * 192 + (id >> 3);  // XCD swizzle over 1536
  const int gb = work / 512;
  const int wk = work - gb * 512;
  const int m0 = (wk >> 2) * 128, n0 = (wk & 3) * 128;
  const int wm = (w & 1) * 64, wn = (w >> 1) * 64;

  const float* Ap = (gb == 0) ? qin : (gb == 1) ? kin : vin;
  const unsigned short* Wp = wb + (size_t)gb * 262144;
  const float* biasp = (gb == 0) ? bq : (gb == 1) ? bk : bv;

  f32x4 acc[4][4];
  const f32x4 z4 = {0.f, 0.f, 0.f, 0.f};
#pragma unroll
  for (int i = 0; i < 4; ++i)
#pragma unroll
    for (int j = 0; j < 4; ++j) acc[i][j] = z4;

  float4v areg[8];
#pragma unroll
  for (int j = 0; j < 8; ++j) {
    const int c = j * 256 + tid;
    areg[j] = *reinterpret_cast<const float4v*>(Ap + (size_t)(m0 + (c >> 4)) * 512 + (c & 15) * 4);
  }

  for (int k0 = 0; k0 < 512; k0 += 64) {
    __syncthreads();  // prev compute done reading LDS; drains in-flight areg loads
    // A: cvt regs -> bf16, swizzled 8B LDS writes (consumes areg)
#pragma unroll
    for (int j = 0; j < 8; ++j) {
      const int c = j * 256 + tid;
      const int row = c >> 4, g4 = c & 15;
      const uint2v pk = {cvtpk(areg[j].x, areg[j].y), cvtpk(areg[j].z, areg[j].w)};
      const int eo = row * 64 + (((g4 >> 1) * 8) ^ ((row & 7) << 3)) + (g4 & 1) * 4;
      *reinterpret_cast<uint2v*>(&As[eo]) = pk;
    }
    // B: global_load_lds, pre-swizzled source
#pragma unroll
    for (int i = 0; i < 4; ++i) {
      const int c = i * 256 + tid;
      const int row = c >> 3, ch = c & 7;
      gld_lds16(Wp + (size_t)(n0 + row) * 512 + k0 + SWZ8(row, ch * 8), &Bs[c * 8]);
    }
    __syncthreads();  // staging visible
    // PREFETCH next A K-slab NOW: overlaps the MFMA phase below; drained by
    // the next iteration's first barrier.
    if (k0 < 448) {
#pragma unroll
      for (int j = 0; j < 8; ++j) {
        const int c = j * 256 + tid;
        areg[j] = *reinterpret_cast<const float4v*>(Ap + (size_t)(m0 + (c >> 4)) * 512 + k0 + 64 +
                                                    (c & 15) * 4);
      }
    }
    bf16x8 af[4][2], bw[4][2];
#pragma unroll
    for (int mt = 0; mt < 4; ++mt)
#pragma unroll
      for (int kk = 0; kk < 2; ++kk)
        af[mt][kk] = ld_bf8(&As[(wm + mt * 16 + lr) * 64 + ((kk * 32 + lg * 8) ^ swz_rd)]);
#pragma unroll
    for (int nt = 0; nt < 4; ++nt)
#pragma unroll
      for (int kk = 0; kk < 2; ++kk)
        bw[nt][kk] = ld_bf8(&Bs[(wn + nt * 16 + lr) * 64 + ((kk * 32 + lg * 8) ^ swz_rd)]);
#pragma unroll
    for (int kk = 0; kk < 2; ++kk)
#pragma unroll
      for (int mt = 0; mt < 4; ++mt)
#pragma unroll
        for (int nt = 0; nt < 4; ++nt)
          acc[mt][nt] =
              __builtin_amdgcn_mfma_f32_16x16x32_bf16(af[mt][kk], bw[nt][kk], acc[mt][nt], 0, 0, 0);
  }

#pragma unroll
  for (int nt = 0; nt < 4; ++nt) {
    const int n = n0 + wn + nt * 16 + lr;
    const float bias = biasp[n];
#pragma unroll
    for (int mt = 0; mt < 4; ++mt) {
#pragma unroll
      for (int j = 0; j < 4; ++j) {
        const int m = m0 + wm + mt * 16 + lg * 4 + j;
        float v = acc[mt][nt][j] + bias;
        const int bb = m >> 11, t = m & 2047;
        const int hh = n >> 6, d = n & 63;
        if (gb == 0) {
          v *= QSCALE;  // fold 1/sqrt(dk)*log2e into q
          q_scr[(((size_t)(bb * 8 + hh) * 2048 + t) << 6) + d] = f2bf(v);
        } else if (gb == 1) {
          k_scr[(((size_t)(bb * 8 + hh) * 2048 + t) << 6) + d] = f2bf(v);
        } else {
          // pi: bits {0,1}->{0,1}, {2,3}->{3,4}, {4}->{2} within each 32-block
          const int tp = (t & ~31) | (((t >> 2) & 3) << 3) | (((t >> 4) & 1) << 2) | (t & 3);
          vT_scr[(((size_t)(bb * 8 + hh) * 64 + d) << 11) + tp] = f2bf(v);
        }
      }
    }
  }
}

// ---------------- flash attention: 8 waves x 16 q-rows, KVBLK=64 [R9/R10-proven] --
__global__ __launch_bounds__(512, 4) void attn_k(
    const unsigned short* __restrict__ qg, const unsigned short* __restrict__ kg,
    const unsigned short* __restrict__ vtg, const unsigned long long* __restrict__ mb,
    unsigned short* __restrict__ xg) {
  __shared__ unsigned short Ks[2][64 * 64];
  __shared__ unsigned short Vts[2][64 * 64];

  const int tid = threadIdx.x;
  const int lane = tid & 63, w = tid >> 6;  // w in [0,8)
  const int lr = lane & 15, lg = lane >> 4;
  const int swz_rd = (lr & 7) << 3;
  const int id = blockIdx.x;
  const int work = (id & 7) * 128 + (id >> 3);  // XCD swizzle: one bh per XCD chunk
  const int bh = work >> 4, qt0 = work & 15;
  const int b = bh >> 3, h = bh & 7;
  const int q0 = qt0 * 128;

  bf16x8 aq[2];
#pragma unroll
  for (int kk = 0; kk < 2; ++kk)
    aq[kk] = ld_bf8(qg + ((size_t)bh * T_N + q0 + w * 16 + lr) * DK_N + kk * 32 + lg * 8);

  const int krow = tid >> 3, kch = tid & 7;
  const unsigned short* kp =
      kg + (size_t)bh * (T_N * DK_N) + krow * 64 + SWZ8(krow, kch * 8);
  const unsigned short* vp =
      vtg + ((size_t)bh * DK_N + krow) * T_N + SWZ8(krow, kch * 8);
  const unsigned long long* mp = mb + ((size_t)b * T_N + q0 + w * 16 + lr) * (T_N / 64);

  f32x4 OT[4];
  float rsacc = 0.f;
  const f32x4 z4 = {0.f, 0.f, 0.f, 0.f};
#pragma unroll
  for (int dt = 0; dt < 4; ++dt) OT[dt] = z4;

  f32x4 ST[4];
  bf16x8 pfrag[2];
  unsigned long long mc, mn = 0;

#define STAGE(PB)                        \
  {                                      \
    gld_lds16(kp, &Ks[PB][tid * 8]);     \
    gld_lds16(vp, &Vts[PB][tid * 8]);    \
    kp += 4096; vp += 64;                \
  }

#define QKT_BLOCK(CUR)                                                                      \
  {                                                                                         \
    __builtin_amdgcn_s_setprio(1);                                                          \
    _Pragma("unroll") for (int st = 0; st < 4; ++st) {                                      \
      const bf16x8 kb0 = ld_bf8(&Ks[CUR][(st * 16 + lr) * 64 + ((lg * 8) ^ swz_rd)]);       \
      const bf16x8 kb1 = ld_bf8(&Ks[CUR][(st * 16 + lr) * 64 + ((32 + lg * 8) ^ swz_rd)]);  \
      f32x4 a_ = __builtin_amdgcn_mfma_f32_16x16x32_bf16(kb0, aq[0], z4, 0, 0, 0);          \
      ST[st] = __builtin_amdgcn_mfma_f32_16x16x32_bf16(kb1, aq[1], a_, 0, 0, 0);            \
    }                                                                                       \
    __builtin_amdgcn_s_setprio(0);                                                          \
  }

#define SOFTMAX_BLOCK()                                                                     \
  {                                                                                         \
    float sv[4][4];                                                                         \
    _Pragma("unroll") for (int st = 0; st < 4; ++st) {                                      \
      const unsigned nib = (unsigned)(mc >> (st * 16 + lg * 4)) & 0xFu;                     \
      _Pragma("unroll") for (int j = 0; j < 4; ++j) {                                       \
        float e = EXP2F(ST[st][j]);                                                         \
        e = ((nib >> j) & 1u) ? 0.f : e;                                                    \
        sv[st][j] = e;                                                                      \
      }                                                                                     \
    }                                                                                       \
    rsacc += (((sv[0][0] + sv[0][1]) + (sv[0][2] + sv[0][3])) +                             \
              ((sv[1][0] + sv[1][1]) + (sv[1][2] + sv[1][3]))) +                            \
             (((sv[2][0] + sv[2][1]) + (sv[2][2] + sv[2][3])) +                             \
              ((sv[3][0] + sv[3][1]) + (sv[3][2] + sv[3][3])));                             \
    uint4v pk0_, pk1_;                                                                      \
    pk0_.x = cvtpk(sv[0][0], sv[0][1]); pk0_.y = cvtpk(sv[0][2], sv[0][3]);                 \
    pk0_.z = cvtpk(sv[1][0], sv[1][1]); pk0_.w = cvtpk(sv[1][2], sv[1][3]);                 \
    pk1_.x = cvtpk(sv[2][0], sv[2][1]); pk1_.y = cvtpk(sv[2][2], sv[2][3]);                 \
    pk1_.z = cvtpk(sv[3][0], sv[3][1]); pk1_.w = cvtpk(sv[3][2], sv[3][3]);                 \
    pfrag[0] = __builtin_bit_cast(bf16x8, pk0_);                                            \
    pfrag[1] = __builtin_bit_cast(bf16x8, pk1_);                                            \
  }

#define PV_BLOCK(PRV)                                                                       \
  {                                                                                         \
    __builtin_amdgcn_s_setprio(1);                                                          \
    _Pragma("unroll") for (int dt = 0; dt < 4; ++dt) {                                      \
      const bf16x8 v0 = ld_bf8(&Vts[PRV][(dt * 16 + lr) * 64 + ((lg * 8) ^ swz_rd)]);       \
      const bf16x8 v1 = ld_bf8(&Vts[PRV][(dt * 16 + lr) * 64 + ((32 + lg * 8) ^ swz_rd)]);  \
      f32x4 o_ = __builtin_amdgcn_mfma_f32_16x16x32_bf16(v0, pfrag[0], OT[dt], 0, 0, 0);    \
      OT[dt] = __builtin_amdgcn_mfma_f32_16x16x32_bf16(v1, pfrag[1], o_, 0, 0, 0);          \
    }                                                                                       \
    __builtin_amdgcn_s_setprio(0);                                                          \
  }

  STAGE(0);
  mc = mp[0];
  __syncthreads();
  QKT_BLOCK(0);
  STAGE(1);
  mn = mp[1];
  SOFTMAX_BLOCK();
  mc = mn;

#define ITER(KT, CUR, LAST)            \
  {                                    \
    PV_BLOCK(CUR ^ 1);                 \
    __syncthreads();                   \
    QKT_BLOCK(CUR);                    \
    if (!(LAST)) {                     \
      STAGE(CUR ^ 1);                  \
      mn = mp[(KT) + 1];               \
    }                                  \
    SOFTMAX_BLOCK();                   \
    mc = mn;                           \
  }

  ITER(1, 1, 0)
  for (int kt0 = 2; kt0 < 30; kt0 += 2) {
    ITER(kt0, 0, 0)
    ITER(kt0 + 1, 1, 0)
  }
  ITER(30, 0, 0)
  ITER(31, 1, 1)
  PV_BLOCK(1);
#undef ITER
#undef STAGE
#undef QKT_BLOCK
#undef SOFTMAX_BLOCK
#undef PV_BLOCK

  {
    float l = rsacc;
    l += __shfl_xor(l, 16);
    l += __shfl_xor(l, 32);
    const float inv = (l > 0.f) ? 1.f / l : 0.f;
    const int q = q0 + w * 16 + lr;
#pragma unroll
    for (int dt = 0; dt < 4; ++dt) {
      uint2v o;
      o.x = cvtpk(OT[dt][0] * inv, OT[dt][1] * inv);
      o.y = cvtpk(OT[dt][2] * inv, OT[dt][3] * inv);
      *reinterpret_cast<uint2v*>(xg + ((size_t)(b * T_N + q)) * FDIM_N + h * 64 + dt * 16 +
                                 lg * 4) = o;
    }
  }
}

// ---------------- output GEMM: bf16 A (x) @ Wo^T + bo -> f32 [R6-proven] ------
__global__ __launch_bounds__(256, 3) void gemm_out_k(const unsigned short* __restrict__ Ap,
                                                     const unsigned short* __restrict__ Wp,
                                                     const float* __restrict__ biasp,
                                                     float* __restrict__ Cp) {
  __shared__ unsigned short As[128 * 64];
  __shared__ unsigned short Bs[128 * 64];
  const int tid = threadIdx.x;
  const int lane = tid & 63, w = tid >> 6;
  const int lr = lane & 15, lg = lane >> 4;
  const int id = blockIdx.x;
  const int work = (id & 7) * 64 + (id >> 3);  // XCD swizzle over 512
  const int m0 = (work >> 2) * 128, n0 = (work & 3) * 128;
  const int wm = (w & 1) * 64, wn = (w >> 1) * 64;
  const int swz_rd = (lr & 7) << 3;

  f32x4 acc[4][4];
  const f32x4 z4 = {0.f, 0.f, 0.f, 0.f};
#pragma unroll
  for (int i = 0; i < 4; ++i)
#pragma unroll
    for (int j = 0; j < 4; ++j) acc[i][j] = z4;

  for (int k0 = 0; k0 < 512; k0 += 64) {
    __syncthreads();
#pragma unroll
    for (int i = 0; i < 4; ++i) {
      const int c = i * 256 + tid;
      const int row = c >> 3, ch = c & 7;
      const int sw = SWZ8(row, ch * 8);
      gld_lds16(Ap + (size_t)(m0 + row) * 512 + k0 + sw, &As[c * 8]);
      gld_lds16(Wp + (size_t)(n0 + row) * 512 + k0 + sw, &Bs[c * 8]);
    }
    __syncthreads();
    bf16x8 af[4][2], bw[4][2];
#pragma unroll
    for (int mt = 0; mt < 4; ++mt)
#pragma unroll
      for (int kk = 0; kk < 2; ++kk)
        af[mt][kk] = ld_bf8(&As[(wm + mt * 16 + lr) * 64 + ((kk * 32 + lg * 8) ^ swz_rd)]);
#pragma unroll
    for (int nt = 0; nt < 4; ++nt)
#pragma unroll
      for (int kk = 0; kk < 2; ++kk)
        bw[nt][kk] = ld_bf8(&Bs[(wn + nt * 16 + lr) * 64 + ((kk * 32 + lg * 8) ^ swz_rd)]);
#pragma unroll
    for (int kk = 0; kk < 2; ++kk)
#pragma unroll
      for (int mt = 0; mt < 4; ++mt)
#pragma unroll
        for (int nt = 0; nt < 4; ++nt)
          acc[mt][nt] =
              __builtin_amdgcn_mfma_f32_16x16x32_bf16(af[mt][kk], bw[nt][kk], acc[mt][nt], 0, 0, 0);
  }

#pragma unroll
  for (int nt = 0; nt < 4; ++nt) {
    const int n = n0 + wn + nt * 16 + lr;
    const float bias = biasp[n];
#pragma unroll
    for (int mt = 0; mt < 4; ++mt) {
#pragma unroll
      for (int j = 0; j < 4; ++j) {
        const int m = m0 + wm + mt * 16 + lg * 4 + j;
        Cp[(size_t)m * 512 + n] = acc[mt][nt][j] + bias;
      }
    }
  }
}

extern "C" void kernel_launch(void* const* d_in, const int* in_sizes, int n_in,
                              void* d_out, int out_size, void* d_ws, size_t ws_size,
                              hipStream_t stream) {
  const float* query = (const float*)d_in[0];
  const float* key = (const float*)d_in[1];
  const float* value = (const float*)d_in[2];
  const int* mask = (const int*)d_in[3];
  const float* Wq = (const float*)d_in[4];
  const float* bq = (const float*)d_in[5];
  const float* Wk = (const float*)d_in[6];
  const float* bk = (const float*)d_in[7];
  const float* Wv = (const float*)d_in[8];
  const float* bv = (const float*)d_in[9];
  const float* Wo = (const float*)d_in[10];
  const float* bo = (const float*)d_in[11];

  const size_t NE = (size_t)16384 * 512;
  const size_t WE = (size_t)512 * 512;
  unsigned short* wqb = (unsigned short*)d_ws;  // 4 weights bf16
  unsigned short* q_scr = wqb + 4 * WE;
  unsigned short* k_scr = q_scr + NE;
  unsigned short* vT_scr = k_scr + NE;
  unsigned short* x_scr = vT_scr + NE;
  unsigned long long* mbits = (unsigned long long*)(x_scr + NE);

  prep_k<<<2560, 256, 0, stream>>>(mask, Wq, Wk, Wv, Wo, wqb, mbits);
  proj_k<<<1536, 256, 0, stream>>>(query, key, value, wqb, bq, bk, bv, q_scr, k_scr, vT_scr);
  attn_k<<<1024, 512, 0, stream>>>(q_scr, k_scr, vT_scr, mbits, x_scr);
  gemm_out_k<<<512, 256, 0, stream>>>(x_scr, wqb + 3 * WE, bo, (float*)d_out);
}

// Round 12
// 214.791 us; speedup vs baseline: 1.1569x; 1.1085x over previous
//
#include <hip/hip_runtime.h>
#include <hip/hip_bf16.h>
#include <stdint.h>

#define B_N 8
#define T_N 2048
#define FDIM_N 512
#define H_N 8
#define DK_N 64

typedef float f32x4 __attribute__((ext_vector_type(4)));
typedef float float4v __attribute__((ext_vector_type(4)));
typedef __bf16 bf16x8 __attribute__((ext_vector_type(8)));
typedef unsigned short ushort8v __attribute__((ext_vector_type(8)));
typedef unsigned int uint2v __attribute__((ext_vector_type(2)));
typedef unsigned int uint4v __attribute__((ext_vector_type(4)));

#if __has_builtin(__builtin_amdgcn_exp2f)
#define EXP2F(x) __builtin_amdgcn_exp2f(x)
#else
#define EXP2F(x) exp2f(x)
#endif

static __device__ __forceinline__ unsigned short f2bf(float f) {
  unsigned int u = __builtin_bit_cast(unsigned int, f);
  u += 0x7fffu + ((u >> 16) & 1u);
  return (unsigned short)(u >> 16);
}

// v_cvt_pk_bf16_f32: lo -> bits[15:0], hi -> bits[31:16] (RNE)
static __device__ __forceinline__ unsigned cvtpk(float lo, float hi) {
  unsigned r;
  asm("v_cvt_pk_bf16_f32 %0, %1, %2" : "=v"(r) : "v"(lo), "v"(hi));
  return r;
}

static __device__ __forceinline__ void gld_lds16(const void* g, void* l) {
  __builtin_amdgcn_global_load_lds(
      (const __attribute__((address_space(1))) unsigned int*)g,
      (__attribute__((address_space(3))) unsigned int*)l, 16, 0, 0);
}

static __device__ __forceinline__ bf16x8 ld_bf8(const unsigned short* p) {
  return *reinterpret_cast<const bf16x8*>(p);
}

// elem-offset XOR swizzle for 64-elem bf16 rows (8-elem granules)
#define SWZ8(row, colE) ((colE) ^ (((row) & 7) << 3))

// combined softmax scale: 1/sqrt(64) * log2(e)  (exp2-domain softmax, no-max)
#define QSCALE 0.1803368801111244f

// ---------------- prep: mask pack + weight cvt + qkv input cvt (all BW-bound) -
// blocks [0,2048): mask int32 -> u64 bitmask (grid-stride)
// blocks [2048,2560): 4 weights f32 -> bf16
// blocks [2560,4096): q,k,v f32 -> bf16 (grid-stride; per-sel base, off index)
__global__ __launch_bounds__(256) void prep_k(
    const int* __restrict__ m, const float* __restrict__ w0, const float* __restrict__ w1,
    const float* __restrict__ w2, const float* __restrict__ w3,
    const float* __restrict__ qin, const float* __restrict__ kin, const float* __restrict__ vin,
    unsigned short* __restrict__ wb, unsigned short* __restrict__ qb,
    unsigned short* __restrict__ kb, unsigned short* __restrict__ vb,
    unsigned long long* __restrict__ mbits) {
  const int bid = blockIdx.x;
  if (bid < 2048) {
    const size_t n = (size_t)B_N * T_N * T_N;
    const size_t stride = (size_t)2048 * 256;
    for (size_t i = (size_t)bid * 256 + threadIdx.x; i < n; i += stride) {
      unsigned long long bl = __ballot(m[i] != 0);
      if ((threadIdx.x & 63) == 0) mbits[i >> 6] = bl;
    }
  } else if (bid < 2560) {
    const int i = (bid - 2048) * 256 + threadIdx.x;  // [0, 131072)
    const int ws = i >> 15, o = i & 32767;
    const float* w = (ws == 0) ? w0 : (ws == 1) ? w1 : (ws == 2) ? w2 : w3;
    const float4v a = *reinterpret_cast<const float4v*>(w + (size_t)o * 8);
    const float4v b = *reinterpret_cast<const float4v*>(w + (size_t)o * 8 + 4);
    const ushort8v out = {f2bf(a.x), f2bf(a.y), f2bf(a.z), f2bf(a.w),
                          f2bf(b.x), f2bf(b.y), f2bf(b.z), f2bf(b.w)};
    *reinterpret_cast<ushort8v*>(wb + (size_t)i * 8) = out;
  } else {
    const unsigned total = 3u << 20;  // 3 x 2^20 ushort8-chunks
    const unsigned stride = 1536u * 256u;
    for (unsigned i = (bid - 2560) * 256 + threadIdx.x; i < total; i += stride) {
      const unsigned sel = i >> 20, off = i & 0xFFFFFu;
      const float* in = (sel == 0) ? qin : (sel == 1) ? kin : vin;
      unsigned short* out = (sel == 0) ? qb : (sel == 1) ? kb : vb;
      const float4v a = *reinterpret_cast<const float4v*>(in + (size_t)off * 8);
      const float4v b = *reinterpret_cast<const float4v*>(in + (size_t)off * 8 + 4);
      const ushort8v o = {f2bf(a.x), f2bf(a.y), f2bf(a.z), f2bf(a.w),
                          f2bf(b.x), f2bf(b.y), f2bf(b.z), f2bf(b.w)};
      *reinterpret_cast<ushort8v*>(out + (size_t)off * 8) = o;  // off, not i
    }
  }
}

// ---------------- single GEMM, all-bf16 m97 pattern [R3-measured ~14us] -------
// C[m][n] = sum_k A[m][k]*W[n][k] + bias[n]; 512 blocks, one GEMM per launch.
// MODE 0: q (QSCALE, layout0)  1: k (layout0)  2: vT (pi permute)  3: f32 out
template <int MODE>
__global__ __launch_bounds__(256, 3) void gemm_bt_k(const unsigned short* __restrict__ Ap,
                                                    const unsigned short* __restrict__ Wp,
                                                    const float* __restrict__ biasp,
                                                    void* __restrict__ Cp) {
  __shared__ unsigned short As[128 * 64];
  __shared__ unsigned short Bs[128 * 64];
  const int tid = threadIdx.x;
  const int lane = tid & 63, w = tid >> 6;
  const int lr = lane & 15, lg = lane >> 4;
  const int id = blockIdx.x;
  const int work = (id & 7) * 64 + (id >> 3);  // XCD swizzle over 512
  const int m0 = (work >> 2) * 128, n0 = (work & 3) * 128;
  const int wm = (w & 1) * 64, wn = (w >> 1) * 64;
  const int swz_rd = (lr & 7) << 3;

  f32x4 acc[4][4];
  const f32x4 z4 = {0.f, 0.f, 0.f, 0.f};
#pragma unroll
  for (int i = 0; i < 4; ++i)
#pragma unroll
    for (int j = 0; j < 4; ++j) acc[i][j] = z4;

  for (int k0 = 0; k0 < 512; k0 += 64) {
    __syncthreads();
#pragma unroll
    for (int i = 0; i < 4; ++i) {
      const int c = i * 256 + tid;
      const int row = c >> 3, ch = c & 7;
      const int sw = SWZ8(row, ch * 8);
      gld_lds16(Ap + (size_t)(m0 + row) * 512 + k0 + sw, &As[c * 8]);
      gld_lds16(Wp + (size_t)(n0 + row) * 512 + k0 + sw, &Bs[c * 8]);
    }
    __syncthreads();
    bf16x8 af[4][2], bw[4][2];
#pragma unroll
    for (int mt = 0; mt < 4; ++mt)
#pragma unroll
      for (int kk = 0; kk < 2; ++kk)
        af[mt][kk] = ld_bf8(&As[(wm + mt * 16 + lr) * 64 + ((kk * 32 + lg * 8) ^ swz_rd)]);
#pragma unroll
    for (int nt = 0; nt < 4; ++nt)
#pragma unroll
      for (int kk = 0; kk < 2; ++kk)
        bw[nt][kk] = ld_bf8(&Bs[(wn + nt * 16 + lr) * 64 + ((kk * 32 + lg * 8) ^ swz_rd)]);
#pragma unroll
    for (int kk = 0; kk < 2; ++kk)
#pragma unroll
      for (int mt = 0; mt < 4; ++mt)
#pragma unroll
        for (int nt = 0; nt < 4; ++nt)
          acc[mt][nt] =
              __builtin_amdgcn_mfma_f32_16x16x32_bf16(af[mt][kk], bw[nt][kk], acc[mt][nt], 0, 0, 0);
  }

#pragma unroll
  for (int nt = 0; nt < 4; ++nt) {
    const int n = n0 + wn + nt * 16 + lr;
    const float bias = biasp[n];
#pragma unroll
    for (int mt = 0; mt < 4; ++mt) {
#pragma unroll
      for (int j = 0; j < 4; ++j) {
        const int m = m0 + wm + mt * 16 + lg * 4 + j;
        float v = acc[mt][nt][j] + bias;
        const int bb = m >> 11, t = m & 2047;
        const int hh = n >> 6, d = n & 63;
        if constexpr (MODE == 0) {
          v *= QSCALE;  // fold 1/sqrt(dk)*log2e into q
          ((unsigned short*)Cp)[(((size_t)(bb * 8 + hh) * 2048 + t) << 6) + d] = f2bf(v);
        } else if constexpr (MODE == 1) {
          ((unsigned short*)Cp)[(((size_t)(bb * 8 + hh) * 2048 + t) << 6) + d] = f2bf(v);
        } else if constexpr (MODE == 2) {
          // pi: bits {0,1}->{0,1}, {2,3}->{3,4}, {4}->{2} within each 32-block
          const int tp = (t & ~31) | (((t >> 2) & 3) << 3) | (((t >> 4) & 1) << 2) | (t & 3);
          ((unsigned short*)Cp)[(((size_t)(bb * 8 + hh) * 64 + d) << 11) + tp] = f2bf(v);
        } else {
          ((float*)Cp)[(size_t)m * 512 + n] = v;
        }
      }
    }
  }
}

// ---------------- flash attention: 8 waves x 16 q-rows, KVBLK=64 [R9-proven 102us] --
__global__ __launch_bounds__(512, 4) void attn_k(
    const unsigned short* __restrict__ qg, const unsigned short* __restrict__ kg,
    const unsigned short* __restrict__ vtg, const unsigned long long* __restrict__ mb,
    unsigned short* __restrict__ xg) {
  __shared__ unsigned short Ks[2][64 * 64];
  __shared__ unsigned short Vts[2][64 * 64];

  const int tid = threadIdx.x;
  const int lane = tid & 63, w = tid >> 6;  // w in [0,8)
  const int lr = lane & 15, lg = lane >> 4;
  const int swz_rd = (lr & 7) << 3;
  const int id = blockIdx.x;
  const int work = (id & 7) * 128 + (id >> 3);  // XCD swizzle: one bh per XCD chunk
  const int bh = work >> 4, qt0 = work & 15;
  const int b = bh >> 3, h = bh & 7;
  const int q0 = qt0 * 128;

  bf16x8 aq[2];
#pragma unroll
  for (int kk = 0; kk < 2; ++kk)
    aq[kk] = ld_bf8(qg + ((size_t)bh * T_N + q0 + w * 16 + lr) * DK_N + kk * 32 + lg * 8);

  const int krow = tid >> 3, kch = tid & 7;
  const unsigned short* kp =
      kg + (size_t)bh * (T_N * DK_N) + krow * 64 + SWZ8(krow, kch * 8);
  const unsigned short* vp =
      vtg + ((size_t)bh * DK_N + krow) * T_N + SWZ8(krow, kch * 8);
  const unsigned long long* mp = mb + ((size_t)b * T_N + q0 + w * 16 + lr) * (T_N / 64);

  f32x4 OT[4];
  float rsacc = 0.f;
  const f32x4 z4 = {0.f, 0.f, 0.f, 0.f};
#pragma unroll
  for (int dt = 0; dt < 4; ++dt) OT[dt] = z4;

  f32x4 ST[4];
  bf16x8 pfrag[2];
  unsigned long long mc, mn = 0;

#define STAGE(PB)                        \
  {                                      \
    gld_lds16(kp, &Ks[PB][tid * 8]);     \
    gld_lds16(vp, &Vts[PB][tid * 8]);    \
    kp += 4096; vp += 64;                \
  }

#define QKT_BLOCK(CUR)                                                                      \
  {                                                                                         \
    __builtin_amdgcn_s_setprio(1);                                                          \
    _Pragma("unroll") for (int st = 0; st < 4; ++st) {                                      \
      const bf16x8 kb0 = ld_bf8(&Ks[CUR][(st * 16 + lr) * 64 + ((lg * 8) ^ swz_rd)]);       \
      const bf16x8 kb1 = ld_bf8(&Ks[CUR][(st * 16 + lr) * 64 + ((32 + lg * 8) ^ swz_rd)]);  \
      f32x4 a_ = __builtin_amdgcn_mfma_f32_16x16x32_bf16(kb0, aq[0], z4, 0, 0, 0);          \
      ST[st] = __builtin_amdgcn_mfma_f32_16x16x32_bf16(kb1, aq[1], a_, 0, 0, 0);            \
    }                                                                                       \
    __builtin_amdgcn_s_setprio(0);                                                          \
  }

#define SOFTMAX_BLOCK()                                                                     \
  {                                                                                         \
    float sv[4][4];                                                                         \
    _Pragma("unroll") for (int st = 0; st < 4; ++st) {                                      \
      const unsigned nib = (unsigned)(mc >> (st * 16 + lg * 4)) & 0xFu;                     \
      _Pragma("unroll") for (int j = 0; j < 4; ++j) {                                       \
        float e = EXP2F(ST[st][j]);                                                         \
        e = ((nib >> j) & 1u) ? 0.f : e;                                                    \
        sv[st][j] = e;                                                                      \
      }                                                                                     \
    }                                                                                       \
    rsacc += (((sv[0][0] + sv[0][1]) + (sv[0][2] + sv[0][3])) +                             \
              ((sv[1][0] + sv[1][1]) + (sv[1][2] + sv[1][3]))) +                            \
             (((sv[2][0] + sv[2][1]) + (sv[2][2] + sv[2][3])) +                             \
              ((sv[3][0] + sv[3][1]) + (sv[3][2] + sv[3][3])));                             \
    uint4v pk0_, pk1_;                                                                      \
    pk0_.x = cvtpk(sv[0][0], sv[0][1]); pk0_.y = cvtpk(sv[0][2], sv[0][3]);                 \
    pk0_.z = cvtpk(sv[1][0], sv[1][1]); pk0_.w = cvtpk(sv[1][2], sv[1][3]);                 \
    pk1_.x = cvtpk(sv[2][0], sv[2][1]); pk1_.y = cvtpk(sv[2][2], sv[2][3]);                 \
    pk1_.z = cvtpk(sv[3][0], sv[3][1]); pk1_.w = cvtpk(sv[3][2], sv[3][3]);                 \
    pfrag[0] = __builtin_bit_cast(bf16x8, pk0_);                                            \
    pfrag[1] = __builtin_bit_cast(bf16x8, pk1_);                                            \
  }

#define PV_BLOCK(PRV)                                                                       \
  {                                                                                         \
    __builtin_amdgcn_s_setprio(1);                                                          \
    _Pragma("unroll") for (int dt = 0; dt < 4; ++dt) {                                      \
      const bf16x8 v0 = ld_bf8(&Vts[PRV][(dt * 16 + lr) * 64 + ((lg * 8) ^ swz_rd)]);       \
      const bf16x8 v1 = ld_bf8(&Vts[PRV][(dt * 16 + lr) * 64 + ((32 + lg * 8) ^ swz_rd)]);  \
      f32x4 o_ = __builtin_amdgcn_mfma_f32_16x16x32_bf16(v0, pfrag[0], OT[dt], 0, 0, 0);    \
      OT[dt] = __builtin_amdgcn_mfma_f32_16x16x32_bf16(v1, pfrag[1], o_, 0, 0, 0);          \
    }                                                                                       \
    __builtin_amdgcn_s_setprio(0);                                                          \
  }

  STAGE(0);
  mc = mp[0];
  __syncthreads();
  QKT_BLOCK(0);
  STAGE(1);
  mn = mp[1];
  SOFTMAX_BLOCK();
  mc = mn;

#define ITER(KT, CUR, LAST)            \
  {                                    \
    PV_BLOCK(CUR ^ 1);                 \
    __syncthreads();                   \
    QKT_BLOCK(CUR);                    \
    if (!(LAST)) {                     \
      STAGE(CUR ^ 1);                  \
      mn = mp[(KT) + 1];               \
    }                                  \
    SOFTMAX_BLOCK();                   \
    mc = mn;                           \
  }

  ITER(1, 1, 0)
  for (int kt0 = 2; kt0 < 30; kt0 += 2) {
    ITER(kt0, 0, 0)
    ITER(kt0 + 1, 1, 0)
  }
  ITER(30, 0, 0)
  ITER(31, 1, 1)
  PV_BLOCK(1);
#undef ITER
#undef STAGE
#undef QKT_BLOCK
#undef SOFTMAX_BLOCK
#undef PV_BLOCK

  {
    float l = rsacc;
    l += __shfl_xor(l, 16);
    l += __shfl_xor(l, 32);
    const float inv = (l > 0.f) ? 1.f / l : 0.f;
    const int q = q0 + w * 16 + lr;
#pragma unroll
    for (int dt = 0; dt < 4; ++dt) {
      uint2v o;
      o.x = cvtpk(OT[dt][0] * inv, OT[dt][1] * inv);
      o.y = cvtpk(OT[dt][2] * inv, OT[dt][3] * inv);
      *reinterpret_cast<uint2v*>(xg + ((size_t)(b * T_N + q)) * FDIM_N + h * 64 + dt * 16 +
                                 lg * 4) = o;
    }
  }
}

extern "C" void kernel_launch(void* const* d_in, const int* in_sizes, int n_in,
                              void* d_out, int out_size, void* d_ws, size_t ws_size,
                              hipStream_t stream) {
  const float* query = (const float*)d_in[0];
  const float* key = (const float*)d_in[1];
  const float* value = (const float*)d_in[2];
  const int* mask = (const int*)d_in[3];
  const float* Wq = (const float*)d_in[4];
  const float* bq = (const float*)d_in[5];
  const float* Wk = (const float*)d_in[6];
  const float* bk = (const float*)d_in[7];
  const float* Wv = (const float*)d_in[8];
  const float* bv = (const float*)d_in[9];
  const float* Wo = (const float*)d_in[10];
  const float* bo = (const float*)d_in[11];

  const size_t NE = (size_t)16384 * 512;
  const size_t WE = (size_t)512 * 512;
  unsigned short* qb_in = (unsigned short*)d_ws;  // bf16 inputs
  unsigned short* kb_in = qb_in + NE;
  unsigned short* vb_in = kb_in + NE;
  unsigned short* wqb = vb_in + NE;               // 4 weights bf16
  unsigned short* q_scr = wqb + 4 * WE;
  unsigned short* k_scr = q_scr + NE;
  unsigned short* vT_scr = k_scr + NE;
  unsigned long long* mbits = (unsigned long long*)(vT_scr + NE);
  unsigned short* x_scr = qb_in;  // alias: qb_in dead after gemm_q

  prep_k<<<4096, 256, 0, stream>>>(mask, Wq, Wk, Wv, Wo, query, key, value, wqb, qb_in, kb_in,
                                   vb_in, mbits);
  gemm_bt_k<0><<<512, 256, 0, stream>>>(qb_in, wqb + 0 * WE, bq, q_scr);
  gemm_bt_k<1><<<512, 256, 0, stream>>>(kb_in, wqb + 1 * WE, bk, k_scr);
  gemm_bt_k<2><<<512, 256, 0, stream>>>(vb_in, wqb + 2 * WE, bv, vT_scr);
  attn_k<<<1024, 512, 0, stream>>>(q_scr, k_scr, vT_scr, mbits, x_scr);
  gemm_bt_k<3><<<512, 256, 0, stream>>>(x_scr, wqb + 3 * WE, bo, (float*)d_out);
}

// Round 13
// 213.747 us; speedup vs baseline: 1.1625x; 1.0049x over previous
//
#include <hip/hip_runtime.h>
#include <hip/hip_bf16.h>
#include <stdint.h>

#define B_N 8
#define T_N 2048
#define FDIM_N 512
#define H_N 8
#define DK_N 64

typedef float f32x4 __attribute__((ext_vector_type(4)));
typedef float float4v __attribute__((ext_vector_type(4)));
typedef __bf16 bf16x8 __attribute__((ext_vector_type(8)));
typedef unsigned short ushort8v __attribute__((ext_vector_type(8)));
typedef unsigned int uint2v __attribute__((ext_vector_type(2)));
typedef unsigned int uint4v __attribute__((ext_vector_type(4)));

#if __has_builtin(__builtin_amdgcn_exp2f)
#define EXP2F(x) __builtin_amdgcn_exp2f(x)
#else
#define EXP2F(x) exp2f(x)
#endif

static __device__ __forceinline__ unsigned short f2bf(float f) {
  unsigned int u = __builtin_bit_cast(unsigned int, f);
  u += 0x7fffu + ((u >> 16) & 1u);
  return (unsigned short)(u >> 16);
}

// v_cvt_pk_bf16_f32: lo -> bits[15:0], hi -> bits[31:16] (RNE)
static __device__ __forceinline__ unsigned cvtpk(float lo, float hi) {
  unsigned r;
  asm("v_cvt_pk_bf16_f32 %0, %1, %2" : "=v"(r) : "v"(lo), "v"(hi));
  return r;
}

static __device__ __forceinline__ void gld_lds16(const void* g, void* l) {
  __builtin_amdgcn_global_load_lds(
      (const __attribute__((address_space(1))) unsigned int*)g,
      (__attribute__((address_space(3))) unsigned int*)l, 16, 0, 0);
}

static __device__ __forceinline__ bf16x8 ld_bf8(const unsigned short* p) {
  return *reinterpret_cast<const bf16x8*>(p);
}

// elem-offset XOR swizzle for 64-elem bf16 rows (8-elem granules)
#define SWZ8(row, colE) ((colE) ^ (((row) & 7) << 3))

// combined softmax scale: 1/sqrt(64) * log2(e)  (exp2-domain softmax, no-max)
#define QSCALE 0.1803368801111244f

// ---------------- prep: mask pack + weight cvt + qkv input cvt [R12-proven] ---
__global__ __launch_bounds__(256) void prep_k(
    const int* __restrict__ m, const float* __restrict__ w0, const float* __restrict__ w1,
    const float* __restrict__ w2, const float* __restrict__ w3,
    const float* __restrict__ qin, const float* __restrict__ kin, const float* __restrict__ vin,
    unsigned short* __restrict__ wb, unsigned short* __restrict__ qb,
    unsigned short* __restrict__ kb, unsigned short* __restrict__ vb,
    unsigned long long* __restrict__ mbits) {
  const int bid = blockIdx.x;
  if (bid < 2048) {
    const size_t n = (size_t)B_N * T_N * T_N;
    const size_t stride = (size_t)2048 * 256;
    for (size_t i = (size_t)bid * 256 + threadIdx.x; i < n; i += stride) {
      unsigned long long bl = __ballot(m[i] != 0);
      if ((threadIdx.x & 63) == 0) mbits[i >> 6] = bl;
    }
  } else if (bid < 2560) {
    const int i = (bid - 2048) * 256 + threadIdx.x;  // [0, 131072)
    const int ws = i >> 15, o = i & 32767;
    const float* w = (ws == 0) ? w0 : (ws == 1) ? w1 : (ws == 2) ? w2 : w3;
    const float4v a = *reinterpret_cast<const float4v*>(w + (size_t)o * 8);
    const float4v b = *reinterpret_cast<const float4v*>(w + (size_t)o * 8 + 4);
    const ushort8v out = {f2bf(a.x), f2bf(a.y), f2bf(a.z), f2bf(a.w),
                          f2bf(b.x), f2bf(b.y), f2bf(b.z), f2bf(b.w)};
    *reinterpret_cast<ushort8v*>(wb + (size_t)i * 8) = out;
  } else {
    const unsigned total = 3u << 20;  // 3 x 2^20 ushort8-chunks
    const unsigned stride = 1536u * 256u;
    for (unsigned i = (bid - 2560) * 256 + threadIdx.x; i < total; i += stride) {
      const unsigned sel = i >> 20, off = i & 0xFFFFFu;
      const float* in = (sel == 0) ? qin : (sel == 1) ? kin : vin;
      unsigned short* out = (sel == 0) ? qb : (sel == 1) ? kb : vb;
      const float4v a = *reinterpret_cast<const float4v*>(in + (size_t)off * 8);
      const float4v b = *reinterpret_cast<const float4v*>(in + (size_t)off * 8 + 4);
      const ushort8v o = {f2bf(a.x), f2bf(a.y), f2bf(a.z), f2bf(a.w),
                          f2bf(b.x), f2bf(b.y), f2bf(b.z), f2bf(b.w)};
      *reinterpret_cast<ushort8v*>(out + (size_t)off * 8) = o;
    }
  }
}

// ---------------- single GEMM, all-bf16 m97 pattern [R12-proven] --------------
// MODE 0: q (QSCALE, layout0)  1: k (layout0)  2: vT (pi permute)  3: f32 out
template <int MODE>
__global__ __launch_bounds__(256, 3) void gemm_bt_k(const unsigned short* __restrict__ Ap,
                                                    const unsigned short* __restrict__ Wp,
                                                    const float* __restrict__ biasp,
                                                    void* __restrict__ Cp) {
  __shared__ unsigned short As[128 * 64];
  __shared__ unsigned short Bs[128 * 64];
  const int tid = threadIdx.x;
  const int lane = tid & 63, w = tid >> 6;
  const int lr = lane & 15, lg = lane >> 4;
  const int id = blockIdx.x;
  const int work = (id & 7) * 64 + (id >> 3);  // XCD swizzle over 512
  const int m0 = (work >> 2) * 128, n0 = (work & 3) * 128;
  const int wm = (w & 1) * 64, wn = (w >> 1) * 64;
  const int swz_rd = (lr & 7) << 3;

  f32x4 acc[4][4];
  const f32x4 z4 = {0.f, 0.f, 0.f, 0.f};
#pragma unroll
  for (int i = 0; i < 4; ++i)
#pragma unroll
    for (int j = 0; j < 4; ++j) acc[i][j] = z4;

  for (int k0 = 0; k0 < 512; k0 += 64) {
    __syncthreads();
#pragma unroll
    for (int i = 0; i < 4; ++i) {
      const int c = i * 256 + tid;
      const int row = c >> 3, ch = c & 7;
      const int sw = SWZ8(row, ch * 8);
      gld_lds16(Ap + (size_t)(m0 + row) * 512 + k0 + sw, &As[c * 8]);
      gld_lds16(Wp + (size_t)(n0 + row) * 512 + k0 + sw, &Bs[c * 8]);
    }
    __syncthreads();
    bf16x8 af[4][2], bw[4][2];
#pragma unroll
    for (int mt = 0; mt < 4; ++mt)
#pragma unroll
      for (int kk = 0; kk < 2; ++kk)
        af[mt][kk] = ld_bf8(&As[(wm + mt * 16 + lr) * 64 + ((kk * 32 + lg * 8) ^ swz_rd)]);
#pragma unroll
    for (int nt = 0; nt < 4; ++nt)
#pragma unroll
      for (int kk = 0; kk < 2; ++kk)
        bw[nt][kk] = ld_bf8(&Bs[(wn + nt * 16 + lr) * 64 + ((kk * 32 + lg * 8) ^ swz_rd)]);
#pragma unroll
    for (int kk = 0; kk < 2; ++kk)
#pragma unroll
      for (int mt = 0; mt < 4; ++mt)
#pragma unroll
        for (int nt = 0; nt < 4; ++nt)
          acc[mt][nt] =
              __builtin_amdgcn_mfma_f32_16x16x32_bf16(af[mt][kk], bw[nt][kk], acc[mt][nt], 0, 0, 0);
  }

#pragma unroll
  for (int nt = 0; nt < 4; ++nt) {
    const int n = n0 + wn + nt * 16 + lr;
    const float bias = biasp[n];
#pragma unroll
    for (int mt = 0; mt < 4; ++mt) {
#pragma unroll
      for (int j = 0; j < 4; ++j) {
        const int m = m0 + wm + mt * 16 + lg * 4 + j;
        float v = acc[mt][nt][j] + bias;
        const int bb = m >> 11, t = m & 2047;
        const int hh = n >> 6, d = n & 63;
        if constexpr (MODE == 0) {
          v *= QSCALE;  // fold 1/sqrt(dk)*log2e into q
          ((unsigned short*)Cp)[(((size_t)(bb * 8 + hh) * 2048 + t) << 6) + d] = f2bf(v);
        } else if constexpr (MODE == 1) {
          ((unsigned short*)Cp)[(((size_t)(bb * 8 + hh) * 2048 + t) << 6) + d] = f2bf(v);
        } else if constexpr (MODE == 2) {
          // pi: bits {0,1}->{0,1}, {2,3}->{3,4}, {4}->{2} within each 32-block
          const int tp = (t & ~31) | (((t >> 2) & 3) << 3) | (((t >> 4) & 1) << 2) | (t & 3);
          ((unsigned short*)Cp)[(((size_t)(bb * 8 + hh) * 64 + d) << 11) + tp] = f2bf(v);
        } else {
          ((float*)Cp)[(size_t)m * 512 + n] = v;
        }
      }
    }
  }
}

// ---------------- flash attention: 8 waves x 16 q-rows, KVBLK=64 ----------------
// R12 numerics byte-identical. New: (a) 8 hoisted LDS read pointers (buffer &
// K/V selection folds into ds_read immediates -> ~0 loop address VALU);
// (b) 4-buffer staging, ONE barrier per 2 tiles (16 barriers vs 32).
// Buffer b occupies L[b*8192 .. +8192): K at +0, V at +4096 (shorts).
__global__ __launch_bounds__(512, 4) void attn_k(
    const unsigned short* __restrict__ qg, const unsigned short* __restrict__ kg,
    const unsigned short* __restrict__ vtg, const unsigned long long* __restrict__ mb,
    unsigned short* __restrict__ xg) {
  __shared__ unsigned short L[4 * 8192];  // 64 KB: 4 x {K 64x64, V^T 64x64}

  const int tid = threadIdx.x;
  const int lane = tid & 63, w = tid >> 6;  // w in [0,8)
  const int lr = lane & 15, lg = lane >> 4;
  const int swz_rd = (lr & 7) << 3;
  const int id = blockIdx.x;
  const int work = (id & 7) * 128 + (id >> 3);  // XCD swizzle: one bh per XCD chunk
  const int bh = work >> 4, qt0 = work & 15;
  const int b = bh >> 3, h = bh & 7;
  const int q0 = qt0 * 128;

  bf16x8 aq[2];
#pragma unroll
  for (int kk = 0; kk < 2; ++kk)
    aq[kk] = ld_bf8(qg + ((size_t)bh * T_N + q0 + w * 16 + lr) * DK_N + kk * 32 + lg * 8);

  // hoisted LDS read pointers: same 8 row-addresses serve QKT (K) and PV (V);
  // buffer (+8192*B shorts) and V (+4096) select via compile-time immediates.
  const unsigned short* rp[8];
#pragma unroll
  for (int st = 0; st < 4; ++st) {
    rp[2 * st + 0] = &L[(st * 16 + lr) * 64 + ((lg * 8) ^ swz_rd)];
    rp[2 * st + 1] = &L[(st * 16 + lr) * 64 + ((32 + lg * 8) ^ swz_rd)];
  }

  const int krow = tid >> 3, kch = tid & 7;
  const unsigned short* kp =
      kg + (size_t)bh * (T_N * DK_N) + krow * 64 + SWZ8(krow, kch * 8);
  const unsigned short* vp =
      vtg + ((size_t)bh * DK_N + krow) * T_N + SWZ8(krow, kch * 8);
  const unsigned long long* mp = mb + ((size_t)b * T_N + q0 + w * 16 + lr) * (T_N / 64);

  f32x4 OT[4];
  float rsacc = 0.f;
  const f32x4 z4 = {0.f, 0.f, 0.f, 0.f};
#pragma unroll
  for (int dt = 0; dt < 4; ++dt) OT[dt] = z4;

  f32x4 ST[4];
  bf16x8 pfrag[2];
  unsigned long long mA, mB;

#define STG(B_)                                       \
  {                                                   \
    gld_lds16(kp, &L[(B_) * 8192 + tid * 8]);         \
    gld_lds16(vp, &L[(B_) * 8192 + 4096 + tid * 8]);  \
    kp += 4096; vp += 64;                             \
  }

#define QKT(B_)                                                                             \
  {                                                                                         \
    __builtin_amdgcn_s_setprio(1);                                                          \
    _Pragma("unroll") for (int st = 0; st < 4; ++st) {                                      \
      const bf16x8 kb0 = ld_bf8(rp[2 * st + 0] + (B_) * 8192);                              \
      const bf16x8 kb1 = ld_bf8(rp[2 * st + 1] + (B_) * 8192);                              \
      f32x4 a_ = __builtin_amdgcn_mfma_f32_16x16x32_bf16(kb0, aq[0], z4, 0, 0, 0);          \
      ST[st] = __builtin_amdgcn_mfma_f32_16x16x32_bf16(kb1, aq[1], a_, 0, 0, 0);            \
    }                                                                                       \
    __builtin_amdgcn_s_setprio(0);                                                          \
  }

#define SM(MREG)                                                                            \
  {                                                                                         \
    float sv[4][4];                                                                         \
    _Pragma("unroll") for (int st = 0; st < 4; ++st) {                                      \
      const unsigned nib = (unsigned)((MREG) >> (st * 16 + lg * 4)) & 0xFu;                 \
      _Pragma("unroll") for (int j = 0; j < 4; ++j) {                                       \
        float e = EXP2F(ST[st][j]);                                                         \
        e = ((nib >> j) & 1u) ? 0.f : e;                                                    \
        sv[st][j] = e;                                                                      \
      }                                                                                     \
    }                                                                                       \
    rsacc += (((sv[0][0] + sv[0][1]) + (sv[0][2] + sv[0][3])) +                             \
              ((sv[1][0] + sv[1][1]) + (sv[1][2] + sv[1][3]))) +                            \
             (((sv[2][0] + sv[2][1]) + (sv[2][2] + sv[2][3])) +                             \
              ((sv[3][0] + sv[3][1]) + (sv[3][2] + sv[3][3])));                             \
    uint4v pk0_, pk1_;                                                                      \
    pk0_.x = cvtpk(sv[0][0], sv[0][1]); pk0_.y = cvtpk(sv[0][2], sv[0][3]);                 \
    pk0_.z = cvtpk(sv[1][0], sv[1][1]); pk0_.w = cvtpk(sv[1][2], sv[1][3]);                 \
    pk1_.x = cvtpk(sv[2][0], sv[2][1]); pk1_.y = cvtpk(sv[2][2], sv[2][3]);                 \
    pk1_.z = cvtpk(sv[3][0], sv[3][1]); pk1_.w = cvtpk(sv[3][2], sv[3][3]);                 \
    pfrag[0] = __builtin_bit_cast(bf16x8, pk0_);                                            \
    pfrag[1] = __builtin_bit_cast(bf16x8, pk1_);                                            \
  }

#define PV(B_)                                                                              \
  {                                                                                         \
    __builtin_amdgcn_s_setprio(1);                                                          \
    _Pragma("unroll") for (int dt = 0; dt < 4; ++dt) {                                      \
      const bf16x8 v0 = ld_bf8(rp[2 * dt + 0] + (B_) * 8192 + 4096);                        \
      const bf16x8 v1 = ld_bf8(rp[2 * dt + 1] + (B_) * 8192 + 4096);                        \
      f32x4 o_ = __builtin_amdgcn_mfma_f32_16x16x32_bf16(v0, pfrag[0], OT[dt], 0, 0, 0);    \
      OT[dt] = __builtin_amdgcn_mfma_f32_16x16x32_bf16(v1, pfrag[1], o_, 0, 0, 0);          \
    }                                                                                       \
    __builtin_amdgcn_s_setprio(0);                                                          \
  }

  // ---- prologue: tiles 0,1 staged; tile 0 computed through softmax ----
  STG(0); STG(1);
  mA = mp[0]; mB = mp[1];
  const unsigned long long* mload = mp + 3;
  __syncthreads();
  QKT(0); STG(2); SM(mA); mA = mp[2];  // pfrag(0)

  // ITER2 invariant on entry (T odd): pfrag=SM(T-1), mB=mp[T], mA=mp[T+1];
  // tiles T,T+1 resident; stages T+2,T+3; ONE barrier.
#define ITER2A            /* T % 4 == 1 */                                                  \
  {                                                                                         \
    PV(0); __syncthreads();                                                                 \
    QKT(1); STG(3); SM(mB); mB = mload[0];                                                  \
    PV(1);                                                                                  \
    QKT(2); STG(0); SM(mA); mA = mload[1]; mload += 2;                                      \
  }
#define ITER2B            /* T % 4 == 3 */                                                  \
  {                                                                                         \
    PV(2); __syncthreads();                                                                 \
    QKT(3); STG(1); SM(mB); mB = mload[0];                                                  \
    PV(3);                                                                                  \
    QKT(0); STG(2); SM(mA); mA = mload[1]; mload += 2;                                      \
  }

  for (int i = 0; i < 7; ++i) {
    ITER2A;
    ITER2B;
  }
  // T=29 (last A): stage tile 31 only; no mp[32] read
  {
    PV(0); __syncthreads();
    QKT(1); STG(3); SM(mB); mB = mload[0];
    PV(1);
    QKT(2); SM(mA);
  }
  // tail: tiles 30,31
  PV(2);
  __syncthreads();
  QKT(3); SM(mB);
  PV(3);
#undef ITER2A
#undef ITER2B
#undef STG
#undef QKT
#undef SM
#undef PV

  // ---- epilogue: single l-reduction + store x[b][q][h*64+d] = O^T[d][q]/l ----
  {
    float l = rsacc;
    l += __shfl_xor(l, 16);
    l += __shfl_xor(l, 32);
    const float inv = (l > 0.f) ? 1.f / l : 0.f;
    const int q = q0 + w * 16 + lr;
#pragma unroll
    for (int dt = 0; dt < 4; ++dt) {
      uint2v o;
      o.x = cvtpk(OT[dt][0] * inv, OT[dt][1] * inv);
      o.y = cvtpk(OT[dt][2] * inv, OT[dt][3] * inv);
      *reinterpret_cast<uint2v*>(xg + ((size_t)(b * T_N + q)) * FDIM_N + h * 64 + dt * 16 +
                                 lg * 4) = o;
    }
  }
}

extern "C" void kernel_launch(void* const* d_in, const int* in_sizes, int n_in,
                              void* d_out, int out_size, void* d_ws, size_t ws_size,
                              hipStream_t stream) {
  const float* query = (const float*)d_in[0];
  const float* key = (const float*)d_in[1];
  const float* value = (const float*)d_in[2];
  const int* mask = (const int*)d_in[3];
  const float* Wq = (const float*)d_in[4];
  const float* bq = (const float*)d_in[5];
  const float* Wk = (const float*)d_in[6];
  const float* bk = (const float*)d_in[7];
  const float* Wv = (const float*)d_in[8];
  const float* bv = (const float*)d_in[9];
  const float* Wo = (const float*)d_in[10];
  const float* bo = (const float*)d_in[11];

  const size_t NE = (size_t)16384 * 512;
  const size_t WE = (size_t)512 * 512;
  unsigned short* qb_in = (unsigned short*)d_ws;  // bf16 inputs
  unsigned short* kb_in = qb_in + NE;
  unsigned short* vb_in = kb_in + NE;
  unsigned short* wqb = vb_in + NE;               // 4 weights bf16
  unsigned short* q_scr = wqb + 4 * WE;
  unsigned short* k_scr = q_scr + NE;
  unsigned short* vT_scr = k_scr + NE;
  unsigned long long* mbits = (unsigned long long*)(vT_scr + NE);
  unsigned short* x_scr = qb_in;  // alias: qb_in dead after gemm_q

  prep_k<<<4096, 256, 0, stream>>>(mask, Wq, Wk, Wv, Wo, query, key, value, wqb, qb_in, kb_in,
                                   vb_in, mbits);
  gemm_bt_k<0><<<512, 256, 0, stream>>>(qb_in, wqb + 0 * WE, bq, q_scr);
  gemm_bt_k<1><<<512, 256, 0, stream>>>(kb_in, wqb + 1 * WE, bk, k_scr);
  gemm_bt_k<2><<<512, 256, 0, stream>>>(vb_in, wqb + 2 * WE, bv, vT_scr);
  attn_k<<<1024, 512, 0, stream>>>(q_scr, k_scr, vT_scr, mbits, x_scr);
  gemm_bt_k<3><<<512, 256, 0, stream>>>(x_scr, wqb + 3 * WE, bo, (float*)d_out);
}